// Round 2
// baseline (225.247 us; speedup 1.0000x reference)
//
#include <hip/hip_runtime.h>
#include <math.h>

#define BATCH_N   32768
#define IN_F      784
#define HID_F     256
#define NCLS      10
#define BM        64          // batch rows per block
#define NTHREADS  512         // 8 waves: 2 (row groups) x 4 (col groups)

typedef __attribute__((ext_vector_type(8))) short short8;  // 8 bf16 = one MFMA operand frag
typedef __attribute__((ext_vector_type(4))) float f32x4;

// d_ws layout: w1 pre-converted to split-bf16 "frag images":
//   slot s = (kt*16 + ct)*64 + lane, 16 B each: B-frag elems j=0..7 =
//   w1[n][k], n = ct*16 + (lane&15), k = kt*32 + (lane>>4)*8 + j  (0 if k>=784)
#define WS_W1H 0
#define WS_W1L 409600          // 25*16*64*16
// total d_ws use: 819200 bytes

union S8U { short8 s; uint4 u; };

// fp32x8 -> split bf16 (hi = truncate, lo = exact residual truncated)
__device__ __forceinline__ void cvt8(float4 a, float4 b, short8* hi, short8* lo) {
    const unsigned M = 0xFFFF0000u;
    const unsigned ux = __float_as_uint(a.x), uy = __float_as_uint(a.y),
                   uz = __float_as_uint(a.z), uw = __float_as_uint(a.w),
                   vx = __float_as_uint(b.x), vy = __float_as_uint(b.y),
                   vz = __float_as_uint(b.z), vw = __float_as_uint(b.w);
    S8U h, l;
    h.u.x = (ux >> 16) | (uy & M);
    h.u.y = (uz >> 16) | (uw & M);
    h.u.z = (vx >> 16) | (vy & M);
    h.u.w = (vz >> 16) | (vw & M);
    const float rx = a.x - __uint_as_float(ux & M);   // exact residuals
    const float ry = a.y - __uint_as_float(uy & M);
    const float rz = a.z - __uint_as_float(uz & M);
    const float rw = a.w - __uint_as_float(uw & M);
    const float sx = b.x - __uint_as_float(vx & M);
    const float sy = b.y - __uint_as_float(vy & M);
    const float sz = b.z - __uint_as_float(vz & M);
    const float sw_ = b.w - __uint_as_float(vw & M);
    l.u.x = (__float_as_uint(rx) >> 16) | (__float_as_uint(ry) & M);
    l.u.y = (__float_as_uint(rz) >> 16) | (__float_as_uint(rw) & M);
    l.u.z = (__float_as_uint(sx) >> 16) | (__float_as_uint(sy) & M);
    l.u.w = (__float_as_uint(sz) >> 16) | (__float_as_uint(sw_) & M);
    *hi = h.s; *lo = l.s;
}

// ---- pre-pass: w1 -> split-bf16 frag images in d_ws (runs every launch) ----
__global__ __launch_bounds__(256)
void prep_w1_kernel(const float* __restrict__ w1, char* __restrict__ ws) {
    const int s    = blockIdx.x * 256 + threadIdx.x;   // 25600 slots
    const int lane = s & 63, ct = (s >> 6) & 15, kt = s >> 10;
    const int n    = ct * 16 + (lane & 15);
    const int k0   = kt * 32 + (lane >> 4) * 8;        // either fully <784 or fully pad
    float4 a = make_float4(0.f, 0.f, 0.f, 0.f), b = a;
    if (k0 + 7 < IN_F) {
        const float* p = w1 + (size_t)n * IN_F + k0;
        a = *(const float4*)p;
        b = *(const float4*)(p + 4);
    }
    short8 hi, lo;
    cvt8(a, b, &hi, &lo);
    *(short8*)(ws + WS_W1H + (size_t)s * 16) = hi;
    *(short8*)(ws + WS_W1L + (size_t)s * 16) = lo;
}

// ---- main kernel: LDS-staged A (K=128/round) + register-double-buffered B ----
__global__ __launch_bounds__(NTHREADS, 4)
void mlp_mfma_kernel(const float* __restrict__ x,
                     const char*  __restrict__ wsb,
                     const float* __restrict__ b1,
                     const float* __restrict__ w2,
                     const float* __restrict__ b2,
                     float* __restrict__ out)
{
    // staging: x tile 64 rows x 128 K as split bf16, double-buffered, swizzled:
    // slot(row, ks) = row*16 + (ks ^ (row&7)), ks = 8-elem k-slot (0..15).
    // hid (epilogue) aliases the staging buffers: total LDS = 64 KB.
    __shared__ union {
        struct { short8 xh[2][1024]; short8 xl[2][1024]; } st;  // 64 KB
        float hid[64 * 128];                                     // 32 KB
    } sm;

    const int tid  = threadIdx.x;
    const int lane = tid & 63;
    const int wv   = tid >> 6;
    const int wc   = wv & 3;           // col group: ct = wc*4 + c
    const int wr   = wv >> 2;          // row group
    const int m    = lane & 15;
    const int quad = lane >> 4;
    const int row0 = blockIdx.x * BM;

    // cooperative staging mapping: thread -> (row slr, 16-float chunk ks16)
    const int slr  = tid >> 3;         // 0..63
    const int ks16 = tid & 7;          // 0..7
    const float* xs = x + (size_t)(row0 + slr) * IN_F + ks16 * 16;
    const int wb0 = slr * 16 + (((ks16 * 2)    ) ^ (slr & 7));
    const int wb1 = slr * 16 + (((ks16 * 2) + 1) ^ (slr & 7));

    // A-frag read slots: row = wr*32 + rt*16 + m, ks = ktl*4 + quad
    const int msw = m & 7;
    const int rb0 = (wr * 32 + m) * 16;
    const int rb1 = rb0 + 256;

    // B pointers (w1 frag images)
    const char* bhp = wsb + WS_W1H + ((size_t)(wc * 4) * 64 + lane) * 16;
    const char* blp = wsb + WS_W1L + ((size_t)(wc * 4) * 64 + lane) * 16;

    f32x4 acc[2][4];
    #pragma unroll
    for (int a = 0; a < 2; ++a)
        #pragma unroll
        for (int b = 0; b < 4; ++b)
            acc[a][b] = (f32x4){0.f, 0.f, 0.f, 0.f};

    // ---- prologue: B(kt=0) into current register buffer ----
    short8 bhc[4], blc[4];
    #pragma unroll
    for (int c = 0; c < 4; ++c) {
        bhc[c] = *(const short8*)(bhp + c * 1024);
        blc[c] = *(const short8*)(blp + c * 1024);
    }
    // ---- prologue: stage round 0 (k 0..127, all valid) ----
    {
        const float4 a0 = *(const float4*)(xs);
        const float4 a1 = *(const float4*)(xs + 4);
        const float4 a2 = *(const float4*)(xs + 8);
        const float4 a3 = *(const float4*)(xs + 12);
        short8 h0, l0, h1, l1;
        cvt8(a0, a1, &h0, &l0);
        cvt8(a2, a3, &h1, &l1);
        sm.st.xh[0][wb0] = h0; sm.st.xl[0][wb0] = l0;
        sm.st.xh[0][wb1] = h1; sm.st.xl[0][wb1] = l1;
    }
    __syncthreads();

    int cur = 0;
    for (int r = 0; r < 6; ++r) {                  // rounds 0..5: kt = 4r..4r+3
        const short8* xhr = sm.st.xh[cur];
        const short8* xlr = sm.st.xl[cur];
        // issue next-round x loads early (hidden under 96 MFMAs of this round)
        const int k0n = (r + 1) * 128 + ks16 * 16;
        float4 xa0 = make_float4(0.f, 0.f, 0.f, 0.f), xa1 = xa0, xa2 = xa0, xa3 = xa0;
        if (k0n < IN_F) {                          // uniform-true for r < 5
            const float* p = xs + (r + 1) * 128;
            xa0 = *(const float4*)(p);
            xa1 = *(const float4*)(p + 4);
            xa2 = *(const float4*)(p + 8);
            xa3 = *(const float4*)(p + 12);
        }
        #pragma unroll
        for (int ktl = 0; ktl < 4; ++ktl) {
            const int kt = r * 4 + ktl;
            // prefetch B(kt+1) while computing kt (kt+1 <= 24 always here)
            short8 bhn[4], bln[4];
            #pragma unroll
            for (int c = 0; c < 4; ++c) {
                bhn[c] = *(const short8*)(bhp + (size_t)(kt + 1) * 16384 + c * 1024);
                bln[c] = *(const short8*)(blp + (size_t)(kt + 1) * 16384 + c * 1024);
            }
            __builtin_amdgcn_s_setprio(1);
            #pragma unroll
            for (int rt = 0; rt < 2; ++rt) {
                const int sl = (rt ? rb1 : rb0) + ((ktl * 4 + quad) ^ msw);
                const short8 ah = xhr[sl];
                const short8 al = xlr[sl];
                #pragma unroll
                for (int c = 0; c < 4; ++c) {
                    acc[rt][c] = __builtin_amdgcn_mfma_f32_16x16x32_bf16(ah, bhc[c], acc[rt][c], 0, 0, 0);
                    acc[rt][c] = __builtin_amdgcn_mfma_f32_16x16x32_bf16(al, bhc[c], acc[rt][c], 0, 0, 0);
                    acc[rt][c] = __builtin_amdgcn_mfma_f32_16x16x32_bf16(ah, blc[c], acc[rt][c], 0, 0, 0);
                }
            }
            __builtin_amdgcn_s_setprio(0);
            #pragma unroll
            for (int c = 0; c < 4; ++c) { bhc[c] = bhn[c]; blc[c] = bln[c]; }
        }
        // stage round r+1 into the other buffer (zeros where k >= 784)
        {
            short8 h0, l0, h1, l1;
            cvt8(xa0, xa1, &h0, &l0);
            cvt8(xa2, xa3, &h1, &l1);
            short8* xhw = sm.st.xh[cur ^ 1];
            short8* xlw = sm.st.xl[cur ^ 1];
            xhw[wb0] = h0; xlw[wb0] = l0;
            xhw[wb1] = h1; xlw[wb1] = l1;
        }
        __syncthreads();
        cur ^= 1;
    }

    // ---- final tile kt = 24 (bhc/blc hold B(24) from the last rotation) ----
    {
        const short8* xhr = sm.st.xh[cur];
        const short8* xlr = sm.st.xl[cur];
        __builtin_amdgcn_s_setprio(1);
        #pragma unroll
        for (int rt = 0; rt < 2; ++rt) {
            const int sl = (rt ? rb1 : rb0) + (quad ^ msw);   // ktl = 0
            const short8 ah = xhr[sl];
            const short8 al = xlr[sl];
            #pragma unroll
            for (int c = 0; c < 4; ++c) {
                acc[rt][c] = __builtin_amdgcn_mfma_f32_16x16x32_bf16(ah, bhc[c], acc[rt][c], 0, 0, 0);
                acc[rt][c] = __builtin_amdgcn_mfma_f32_16x16x32_bf16(al, bhc[c], acc[rt][c], 0, 0, 0);
                acc[rt][c] = __builtin_amdgcn_mfma_f32_16x16x32_bf16(ah, blc[c], acc[rt][c], 0, 0, 0);
            }
        }
        __builtin_amdgcn_s_setprio(0);
    }

    // ---- epilogue: two passes over column halves (hid = 64x128 compact) ----
    const int rl    = tid >> 3;        // row 0..63
    const int slice = tid & 7;         // 8 h-slices per row
    const int gb    = (slice >> 1) * 64 + (slice & 1) * 16;  // + 32p + i*4
    const int cb    = slice * 16;      // compact base
    const int sw2   = (rl & 7) << 2;

    float lg[NCLS];
    #pragma unroll
    for (int k = 0; k < NCLS; ++k) lg[k] = 0.f;

    #pragma unroll
    for (int p = 0; p < 2; ++p) {
        __syncthreads();               // p=0: staging reads done; p=1: pass-0 reads done
        // phase 1: bias + relu -> hid, cols c = 2p, 2p+1 (compact, swizzled)
        #pragma unroll
        for (int cl = 0; cl < 2; ++cl) {
            const int c  = 2 * p + cl;
            const int g  = (wc * 4 + c) * 16 + m;      // global hidden col
            const float bv = b1[g];
            const int cc = wc * 32 + cl * 16 + m;      // compact col
            #pragma unroll
            for (int rt = 0; rt < 2; ++rt)
                #pragma unroll
                for (int reg = 0; reg < 4; ++reg) {
                    const int row = wr * 32 + rt * 16 + quad * 4 + reg;
                    sm.hid[row * 128 + (cc ^ ((row & 7) << 2))] =
                        fmaxf(acc[rt][c][reg] + bv, 0.f);
                }
        }
        __syncthreads();
        // phase 2: partial logits over this pass's 16 compact cols per thread
        #pragma unroll
        for (int i = 0; i < 4; ++i) {
            const float4 h = *(const float4*)(sm.hid + rl * 128 + ((cb + i * 4) ^ sw2));
            const int g4 = gb + 32 * p + i * 4;
            #pragma unroll
            for (int k = 0; k < NCLS; ++k) {
                const float4 w = *(const float4*)(w2 + k * HID_F + g4);
                lg[k] += h.x * w.x + h.y * w.y + h.z * w.z + h.w * w.w;
            }
        }
    }

    // butterfly-reduce the 8 slices (lane bits 0..2), add bias
    #pragma unroll
    for (int k = 0; k < NCLS; ++k) {
        float v = lg[k];
        v += __shfl_xor(v, 1);
        v += __shfl_xor(v, 2);
        v += __shfl_xor(v, 4);
        lg[k] = v + b2[k];
    }
    // softmax (computed redundantly by all 8 slice-lanes of a row)
    float mx = -1e30f;
    #pragma unroll
    for (int k = 0; k < NCLS; ++k) mx = fmaxf(mx, lg[k]);
    float s = 0.f;
    #pragma unroll
    for (int k = 0; k < NCLS; ++k) { lg[k] = __expf(lg[k] - mx); s += lg[k]; }
    const float inv = 1.f / s;
    // select lg[slice] / lg[8+slice] without runtime register indexing (rule #20)
    const float va = (slice & 4)
        ? ((slice & 2) ? ((slice & 1) ? lg[7] : lg[6]) : ((slice & 1) ? lg[5] : lg[4]))
        : ((slice & 2) ? ((slice & 1) ? lg[3] : lg[2]) : ((slice & 1) ? lg[1] : lg[0]));
    const float vb = (slice & 1) ? lg[9] : lg[8];
    float* o = out + (size_t)(row0 + rl) * NCLS;
    o[slice] = va * inv;                               // classes 0..7
    if (slice < 2) o[8 + slice] = vb * inv;            // classes 8,9
}

extern "C" void kernel_launch(void* const* d_in, const int* in_sizes, int n_in,
                              void* d_out, int out_size, void* d_ws, size_t ws_size,
                              hipStream_t stream)
{
    const float* x  = (const float*)d_in[0];
    const float* w1 = (const float*)d_in[1];
    const float* b1 = (const float*)d_in[2];
    const float* w2 = (const float*)d_in[3];
    const float* b2 = (const float*)d_in[4];
    float* out = (float*)d_out;

    // pre-pass: w1 -> split-bf16 frag images (25600 slots; runs every call)
    hipLaunchKernelGGL(prep_w1_kernel, dim3(100), dim3(256), 0, stream,
                       w1, (char*)d_ws);
    // main fused MLP
    hipLaunchKernelGGL(mlp_mfma_kernel, dim3(BATCH_N / BM), dim3(NTHREADS), 0, stream,
                       x, (const char*)d_ws, b1, w2, b2, out);
}

// Round 3
// 215.779 us; speedup vs baseline: 1.0439x; 1.0439x over previous
//
#include <hip/hip_runtime.h>
#include <math.h>

#define BATCH_N   32768
#define IN_F      784
#define HID_F     256
#define NCLS      10
#define BM        64          // batch rows per block
#define NTHREADS  512         // 8 waves: 2 (row groups) x 4 (col groups)

typedef __attribute__((ext_vector_type(8))) short short8;  // 8 bf16 = one MFMA operand frag
typedef __attribute__((ext_vector_type(4))) float f32x4;

// d_ws layout: w1 pre-converted to split-bf16 "frag images":
//   slot s = (kt*16 + ct)*64 + lane, 16 B each: B-frag elems j=0..7 =
//   w1[n][k], n = ct*16 + (lane&15), k = kt*32 + (lane>>4)*8 + j  (0 if k>=784)
#define WS_W1H 0
#define WS_W1L 409600          // 25*16*64*16
// total d_ws use: 819200 bytes

union S8U { short8 s; uint4 u; };

// fp32x8 -> split bf16 (hi = truncate, lo = exact residual truncated)
__device__ __forceinline__ void cvt8(float4 a, float4 b, short8* hi, short8* lo) {
    const unsigned M = 0xFFFF0000u;
    const unsigned ux = __float_as_uint(a.x), uy = __float_as_uint(a.y),
                   uz = __float_as_uint(a.z), uw = __float_as_uint(a.w),
                   vx = __float_as_uint(b.x), vy = __float_as_uint(b.y),
                   vz = __float_as_uint(b.z), vw = __float_as_uint(b.w);
    S8U h, l;
    h.u.x = (ux >> 16) | (uy & M);
    h.u.y = (uz >> 16) | (uw & M);
    h.u.z = (vx >> 16) | (vy & M);
    h.u.w = (vz >> 16) | (vw & M);
    const float rx = a.x - __uint_as_float(ux & M);   // exact residuals
    const float ry = a.y - __uint_as_float(uy & M);
    const float rz = a.z - __uint_as_float(uz & M);
    const float rw = a.w - __uint_as_float(uw & M);
    const float sx = b.x - __uint_as_float(vx & M);
    const float sy = b.y - __uint_as_float(vy & M);
    const float sz = b.z - __uint_as_float(vz & M);
    const float sw_ = b.w - __uint_as_float(vw & M);
    l.u.x = (__float_as_uint(rx) >> 16) | (__float_as_uint(ry) & M);
    l.u.y = (__float_as_uint(rz) >> 16) | (__float_as_uint(rw) & M);
    l.u.z = (__float_as_uint(sx) >> 16) | (__float_as_uint(sy) & M);
    l.u.w = (__float_as_uint(sz) >> 16) | (__float_as_uint(sw_) & M);
    *hi = h.s; *lo = l.s;
}

// ---- pre-pass: w1 -> split-bf16 frag images in d_ws (runs every launch) ----
__global__ __launch_bounds__(256)
void prep_w1_kernel(const float* __restrict__ w1, char* __restrict__ ws) {
    const int s    = blockIdx.x * 256 + threadIdx.x;   // 25600 slots
    const int lane = s & 63, ct = (s >> 6) & 15, kt = s >> 10;
    const int n    = ct * 16 + (lane & 15);
    const int k0   = kt * 32 + (lane >> 4) * 8;        // either fully <784 or fully pad
    float4 a = make_float4(0.f, 0.f, 0.f, 0.f), b = a;
    if (k0 + 7 < IN_F) {
        const float* p = w1 + (size_t)n * IN_F + k0;
        a = *(const float4*)p;
        b = *(const float4*)(p + 4);
    }
    short8 hi, lo;
    cvt8(a, b, &hi, &lo);
    *(short8*)(ws + WS_W1H + (size_t)s * 16) = hi;
    *(short8*)(ws + WS_W1L + (size_t)s * 16) = lo;
}

// async 16B global->LDS (vmcnt-counted, no VGPR round trip; LDS dest must be
// wave-uniform base + lane*16 -> our layout is exactly linear per wave)
__device__ __forceinline__ void gload16(const void* g, void* l) {
    __builtin_amdgcn_global_load_lds(
        (const __attribute__((address_space(1))) void*)g,
        (__attribute__((address_space(3))) void*)l, 16, 0, 0);
}

// inline-asm 16B load: compiler cannot sink/serialize it; result must be
// guarded by our manual s_waitcnt vmcnt(N) + sched_barrier(0) (rule #18)
__device__ __forceinline__ short8 gload_s8(const void* p) {
    short8 r;
    asm volatile("global_load_dwordx4 %0, %1, off" : "=v"(r) : "v"(p));
    return r;
}

// ---- main kernel: async-LDS x ring (depth 4) + asm-pipelined B registers ----
__global__ __launch_bounds__(NTHREADS, 2)
void mlp_mfma_kernel(const float* __restrict__ x,
                     const char*  __restrict__ wsb,
                     const float* __restrict__ b1,
                     const float* __restrict__ w2,
                     const float* __restrict__ b2,
                     float* __restrict__ out)
{
    // xraw[slot][row 0..63][chunk-slot 0..7][16B]; LDS[r][s] holds global
    // chunk s ^ (r&7) (source-swizzled so frag reads spread across banks).
    __shared__ char  xraw[4][8192];     // 32 KB ring of raw fp32 x tiles (K=32 each)
    __shared__ float hid[64 * 128];     // 32 KB epilogue buffer

    const int tid  = threadIdx.x;
    const int lane = tid & 63;
    const int wv   = tid >> 6;
    const int wc   = wv & 3;           // col group: ct = wc*4 + c
    const int wr   = wv >> 2;          // row group
    const int m    = lane & 15;
    const int quad = lane >> 4;
    const int row0 = blockIdx.x * BM;

    // staging map: lane l -> row wv*8 + (l>>3), LDS slot (l&7),
    // fetches global chunk (l&7) ^ (l>>3)  (4 floats = 16B per chunk)
    const int srow = wv * 8 + (lane >> 3);
    const int gch  = (lane & 7) ^ (lane >> 3);
    const float* xg = x + (size_t)(row0 + srow) * IN_F;   // + kt*32 + chunk*4

    // frag read addressing: row = wr*32 + rt*16 + m; chunks 2q, 2q+1
    const int msw = m & 7;
    const int rowbase = (wr * 32 + m) * 128;
    const int o0 = ((2 * quad)     ^ msw) * 16;
    const int o1 = ((2 * quad + 1) ^ msw) * 16;

    // B pointers (w1 frag images)
    const char* bhp = wsb + WS_W1H + ((size_t)(wc * 4) * 64 + lane) * 16;
    const char* blp = wsb + WS_W1L + ((size_t)(wc * 4) * 64 + lane) * 16;

    f32x4 acc[2][4];
    #pragma unroll
    for (int a = 0; a < 2; ++a)
        #pragma unroll
        for (int b = 0; b < 4; ++b)
            acc[a][b] = (f32x4){0.f, 0.f, 0.f, 0.f};

    // ---- prologue: async-stage x(0), x(1); asm-load B(0) ----
    gload16(xg + gch * 4,      &xraw[0][wv * 1024]);
    gload16(xg + 32 + gch * 4, &xraw[1][wv * 1024]);
    short8 bhc[4], blc[4], bhn[4], bln[4];
    #pragma unroll
    for (int c = 0; c < 4; ++c) {
        bhc[c] = gload_s8(bhp + c * 1024);
        blc[c] = gload_s8(blp + c * 1024);
    }

    // ---- main loop: kt = 0..23, one raw barrier per kt, vmcnt never drained ----
    for (int kb = 0; kb < 24; kb += 4) {
        #pragma unroll
        for (int i = 0; i < 4; ++i) {
            const int kt = kb + i;
            // 1. issue x(kt+2) into ring slot (i+2)&3 (clamped at tail; the
            //    clamped duplicate lands in a slot that is never read again)
            {
                const int ktc = (kt + 2 > 24) ? 24 : kt + 2;
                const int cgc = (ktc == 24 && gch > 3) ? 0 : gch;   // stay in-bounds
                gload16(xg + ktc * 32 + cgc * 4, &xraw[(i + 2) & 3][wv * 1024]);
            }
            // 2. issue B(kt+1) (kt+1 <= 24, always valid)
            #pragma unroll
            for (int c = 0; c < 4; ++c) {
                bhn[c] = gload_s8(bhp + (size_t)(kt + 1) * 16384 + c * 1024);
                bln[c] = gload_s8(blp + (size_t)(kt + 1) * 16384 + c * 1024);
            }
            // 3. wait for x(kt) + B(kt): allow the newest 9 (x(kt+2) + B(kt+1))
            asm volatile("s_waitcnt vmcnt(9)");
            __builtin_amdgcn_sched_barrier(0);
            __builtin_amdgcn_s_barrier();          // raw: does NOT drain vmcnt
            __builtin_amdgcn_sched_barrier(0);
            // 4. compute kt from xraw[i] (fp32 -> split bf16 at read) and B regs
            const char* xr = &xraw[i][0];
            __builtin_amdgcn_s_setprio(1);
            #pragma unroll
            for (int rt = 0; rt < 2; ++rt) {
                const float4 fa = *(const float4*)(xr + rowbase + rt * 2048 + o0);
                const float4 fb = *(const float4*)(xr + rowbase + rt * 2048 + o1);
                short8 ah, al;
                cvt8(fa, fb, &ah, &al);
                #pragma unroll
                for (int c = 0; c < 4; ++c) {
                    acc[rt][c] = __builtin_amdgcn_mfma_f32_16x16x32_bf16(ah, bhc[c], acc[rt][c], 0, 0, 0);
                    acc[rt][c] = __builtin_amdgcn_mfma_f32_16x16x32_bf16(al, bhc[c], acc[rt][c], 0, 0, 0);
                    acc[rt][c] = __builtin_amdgcn_mfma_f32_16x16x32_bf16(ah, blc[c], acc[rt][c], 0, 0, 0);
                }
            }
            __builtin_amdgcn_s_setprio(0);
            // 5. rotate B buffers (renamed away by unroll)
            #pragma unroll
            for (int c = 0; c < 4; ++c) { bhc[c] = bhn[c]; blc[c] = bln[c]; }
        }
    }

    // ---- tail kt = 24 (slot 0; k >= 784 -> quads 2,3 zeroed) ----
    {
        asm volatile("s_waitcnt vmcnt(0)");
        __builtin_amdgcn_sched_barrier(0);
        __builtin_amdgcn_s_barrier();
        __builtin_amdgcn_sched_barrier(0);
        const char* xr = &xraw[0][0];
        __builtin_amdgcn_s_setprio(1);
        #pragma unroll
        for (int rt = 0; rt < 2; ++rt) {
            const float4 fa = *(const float4*)(xr + rowbase + rt * 2048 + o0);
            const float4 fb = *(const float4*)(xr + rowbase + rt * 2048 + o1);
            short8 ah, al;
            cvt8(fa, fb, &ah, &al);
            if (quad >= 2) {               // k >= 784: zero the A frags
                const short8 zz = {0, 0, 0, 0, 0, 0, 0, 0};
                ah = zz; al = zz;
            }
            #pragma unroll
            for (int c = 0; c < 4; ++c) {
                acc[rt][c] = __builtin_amdgcn_mfma_f32_16x16x32_bf16(ah, bhc[c], acc[rt][c], 0, 0, 0);
                acc[rt][c] = __builtin_amdgcn_mfma_f32_16x16x32_bf16(al, bhc[c], acc[rt][c], 0, 0, 0);
                acc[rt][c] = __builtin_amdgcn_mfma_f32_16x16x32_bf16(ah, blc[c], acc[rt][c], 0, 0, 0);
            }
        }
        __builtin_amdgcn_s_setprio(0);
    }

    // ---- epilogue: two passes over column halves (hid = 64x128 compact) ----
    const int rl    = tid >> 3;        // row 0..63
    const int slice = tid & 7;         // 8 h-slices per row
    const int gb    = (slice >> 1) * 64 + (slice & 1) * 16;  // + 32p + i*4
    const int cb    = slice * 16;      // compact base
    const int sw2   = (rl & 7) << 2;

    float lg[NCLS];
    #pragma unroll
    for (int k = 0; k < NCLS; ++k) lg[k] = 0.f;

    #pragma unroll
    for (int p = 0; p < 2; ++p) {
        if (p) __syncthreads();        // pass-0 reads done before rewrite
        // phase 1: bias + relu -> hid, cols c = 2p, 2p+1 (compact, swizzled)
        #pragma unroll
        for (int cl = 0; cl < 2; ++cl) {
            const int c  = 2 * p + cl;
            const int g  = (wc * 4 + c) * 16 + m;      // global hidden col
            const float bv = b1[g];
            const int cc = wc * 32 + cl * 16 + m;      // compact col
            #pragma unroll
            for (int rt = 0; rt < 2; ++rt)
                #pragma unroll
                for (int reg = 0; reg < 4; ++reg) {
                    const int row = wr * 32 + rt * 16 + quad * 4 + reg;
                    hid[row * 128 + (cc ^ ((row & 7) << 2))] =
                        fmaxf(acc[rt][c][reg] + bv, 0.f);
                }
        }
        __syncthreads();
        // phase 2: partial logits over this pass's 16 compact cols per thread
        #pragma unroll
        for (int i = 0; i < 4; ++i) {
            const float4 h = *(const float4*)(hid + rl * 128 + ((cb + i * 4) ^ sw2));
            const int g4 = gb + 32 * p + i * 4;
            #pragma unroll
            for (int k = 0; k < NCLS; ++k) {
                const float4 w = *(const float4*)(w2 + k * HID_F + g4);
                lg[k] += h.x * w.x + h.y * w.y + h.z * w.z + h.w * w.w;
            }
        }
    }

    // butterfly-reduce the 8 slices (lane bits 0..2), add bias
    #pragma unroll
    for (int k = 0; k < NCLS; ++k) {
        float v = lg[k];
        v += __shfl_xor(v, 1);
        v += __shfl_xor(v, 2);
        v += __shfl_xor(v, 4);
        lg[k] = v + b2[k];
    }
    // softmax (computed redundantly by all 8 slice-lanes of a row)
    float mx = -1e30f;
    #pragma unroll
    for (int k = 0; k < NCLS; ++k) mx = fmaxf(mx, lg[k]);
    float s = 0.f;
    #pragma unroll
    for (int k = 0; k < NCLS; ++k) { lg[k] = __expf(lg[k] - mx); s += lg[k]; }
    const float inv = 1.f / s;
    // select lg[slice] / lg[8+slice] without runtime register indexing (rule #20)
    const float va = (slice & 4)
        ? ((slice & 2) ? ((slice & 1) ? lg[7] : lg[6]) : ((slice & 1) ? lg[5] : lg[4]))
        : ((slice & 2) ? ((slice & 1) ? lg[3] : lg[2]) : ((slice & 1) ? lg[1] : lg[0]));
    const float vb = (slice & 1) ? lg[9] : lg[8];
    float* o = out + (size_t)(row0 + rl) * NCLS;
    o[slice] = va * inv;                               // classes 0..7
    if (slice < 2) o[8 + slice] = vb * inv;            // classes 8,9
}

extern "C" void kernel_launch(void* const* d_in, const int* in_sizes, int n_in,
                              void* d_out, int out_size, void* d_ws, size_t ws_size,
                              hipStream_t stream)
{
    const float* x  = (const float*)d_in[0];
    const float* w1 = (const float*)d_in[1];
    const float* b1 = (const float*)d_in[2];
    const float* w2 = (const float*)d_in[3];
    const float* b2 = (const float*)d_in[4];
    float* out = (float*)d_out;

    // pre-pass: w1 -> split-bf16 frag images (25600 slots; runs every call)
    hipLaunchKernelGGL(prep_w1_kernel, dim3(100), dim3(256), 0, stream,
                       w1, (char*)d_ws);
    // main fused MLP
    hipLaunchKernelGGL(mlp_mfma_kernel, dim3(BATCH_N / BM), dim3(NTHREADS), 0, stream,
                       x, (const char*)d_ws, b1, w2, b2, out);
}

// Round 4
// 213.526 us; speedup vs baseline: 1.0549x; 1.0106x over previous
//
#include <hip/hip_runtime.h>
#include <math.h>

#define BATCH_N   32768
#define IN_F      784
#define HID_F     256
#define NCLS      10
#define BM        64          // batch rows per block
#define NTHREADS  512         // 8 waves: each owns 2 column-tiles, all 4 row-tiles

typedef __attribute__((ext_vector_type(8))) short short8;  // 8 bf16 = one MFMA operand frag
typedef __attribute__((ext_vector_type(4))) float f32x4;

// d_ws layout: w1 pre-converted to split-bf16 "frag images":
//   slot s = (kt*16 + ct)*64 + lane, 16 B each: B-frag elems j=0..7 =
//   w1[n][k], n = ct*16 + (lane&15), k = kt*32 + (lane>>4)*8 + j  (0 if k>=784)
#define WS_W1H 0
#define WS_W1L 409600          // 25*16*64*16
// total d_ws use: 819200 bytes

union S8U { short8 s; uint4 u; };

// fp32x8 -> split bf16 (hi = truncate, lo = exact residual truncated)
__device__ __forceinline__ void cvt8(float4 a, float4 b, short8* hi, short8* lo) {
    const unsigned M = 0xFFFF0000u;
    const unsigned ux = __float_as_uint(a.x), uy = __float_as_uint(a.y),
                   uz = __float_as_uint(a.z), uw = __float_as_uint(a.w),
                   vx = __float_as_uint(b.x), vy = __float_as_uint(b.y),
                   vz = __float_as_uint(b.z), vw = __float_as_uint(b.w);
    S8U h, l;
    h.u.x = (ux >> 16) | (uy & M);
    h.u.y = (uz >> 16) | (uw & M);
    h.u.z = (vx >> 16) | (vy & M);
    h.u.w = (vz >> 16) | (vw & M);
    const float rx = a.x - __uint_as_float(ux & M);
    const float ry = a.y - __uint_as_float(uy & M);
    const float rz = a.z - __uint_as_float(uz & M);
    const float rw = a.w - __uint_as_float(uw & M);
    const float sx = b.x - __uint_as_float(vx & M);
    const float sy = b.y - __uint_as_float(vy & M);
    const float sz = b.z - __uint_as_float(vz & M);
    const float sw_ = b.w - __uint_as_float(vw & M);
    l.u.x = (__float_as_uint(rx) >> 16) | (__float_as_uint(ry) & M);
    l.u.y = (__float_as_uint(rz) >> 16) | (__float_as_uint(rw) & M);
    l.u.z = (__float_as_uint(sx) >> 16) | (__float_as_uint(sy) & M);
    l.u.w = (__float_as_uint(sz) >> 16) | (__float_as_uint(sw_) & M);
    *hi = h.s; *lo = l.s;
}

// fp32x4 -> split bf16 (4 hi in uint2, 4 lo in uint2); same packing convention
__device__ __forceinline__ void cvt4(float4 a, uint2* h, uint2* l) {
    const unsigned M = 0xFFFF0000u;
    const unsigned ux = __float_as_uint(a.x), uy = __float_as_uint(a.y),
                   uz = __float_as_uint(a.z), uw = __float_as_uint(a.w);
    h->x = (ux >> 16) | (uy & M);
    h->y = (uz >> 16) | (uw & M);
    const float rx = a.x - __uint_as_float(ux & M);
    const float ry = a.y - __uint_as_float(uy & M);
    const float rz = a.z - __uint_as_float(uz & M);
    const float rw = a.w - __uint_as_float(uw & M);
    l->x = (__float_as_uint(rx) >> 16) | (__float_as_uint(ry) & M);
    l->y = (__float_as_uint(rz) >> 16) | (__float_as_uint(rw) & M);
}

// ---- pre-pass: w1 -> split-bf16 frag images in d_ws (runs every launch) ----
__global__ __launch_bounds__(256)
void prep_w1_kernel(const float* __restrict__ w1, char* __restrict__ ws) {
    const int s    = blockIdx.x * 256 + threadIdx.x;   // 25600 slots
    const int lane = s & 63, ct = (s >> 6) & 15, kt = s >> 10;
    const int n    = ct * 16 + (lane & 15);
    const int k0   = kt * 32 + (lane >> 4) * 8;
    float4 a = make_float4(0.f, 0.f, 0.f, 0.f), b = a;
    if (k0 + 7 < IN_F) {
        const float* p = w1 + (size_t)n * IN_F + k0;
        a = *(const float4*)p;
        b = *(const float4*)(p + 4);
    }
    short8 hi, lo;
    cvt8(a, b, &hi, &lo);
    *(short8*)(ws + WS_W1H + (size_t)s * 16) = hi;
    *(short8*)(ws + WS_W1L + (size_t)s * 16) = lo;
}

// async 16B global->LDS (vmcnt-counted; dest = wave-uniform base + lane*16)
__device__ __forceinline__ void gload16(const void* g, void* l) {
    __builtin_amdgcn_global_load_lds(
        (const __attribute__((address_space(1))) void*)g,
        (__attribute__((address_space(3))) void*)l, 16, 0, 0);
}

// inline-asm 16B load: cannot be sunk; guard with manual vmcnt + sched_barrier
__device__ __forceinline__ short8 gload_s8(const void* p) {
    short8 r;
    asm volatile("global_load_dwordx4 %0, %1, off" : "=v"(r) : "v"(p));
    return r;
}

// ---- main kernel: dedup'd B (8 ct-groups), convert-phase A, deep pipeline ----
__global__ __launch_bounds__(NTHREADS, 4)
void mlp_mfma_kernel(const float* __restrict__ x,
                     const char*  __restrict__ wsb,
                     const float* __restrict__ b1,
                     const float* __restrict__ w2,
                     const float* __restrict__ b2,
                     float* __restrict__ out)
{
    // raw: ring of 4 x-tiles (64 rows x 32 k fp32, source-swizzled chunks)
    // convh/convl: double-buffered converted tile (64 rows x 32 k bf16, swizzled)
    // hid: epilogue 64x256 f32, aliased over all staging (staging dead by then)
    __shared__ union {
        struct {
            char raw[4][8192];    // 32 KB
            char convh[2][4096];  // 8 KB
            char convl[2][4096];  // 8 KB
        } s;
        float hid[64 * 256];      // 64 KB
    } sm;

    const int tid  = threadIdx.x;
    const int lane = tid & 63;
    const int wv   = tid >> 6;         // wave = ct pair: cols (wv*2+c)*16+m
    const int m    = lane & 15;
    const int quad = lane >> 4;
    const int row0 = blockIdx.x * BM;

    // staging map: lane l -> row wv*8 + (l>>3), LDS slot l&7 holds global
    // chunk (l&7)^(row&7)  (16B chunks; source-swizzled)
    const int srow = wv * 8 + (lane >> 3);
    const int gch  = (lane & 7) ^ (lane >> 3);
    const float* xg = x + (size_t)(row0 + srow) * IN_F;   // + kt*32 + chunk*4

    // convert map: thread t handles raw row cr = t>>3, slot t&7 = chunk cc
    const int cr  = tid >> 3;
    const int cc  = (tid & 7) ^ (cr & 7);
    const int cq  = cc >> 1;
    const int conv_off = cr * 64 + ((cq ^ ((cr >> 1) & 3)) << 4) + (cc & 1) * 8;

    // frag read: row = rt*16 + m, q-slot swizzle (quad ^ ((m>>1)&3))
    const int fbase = m * 64 + ((quad ^ ((m >> 1) & 3)) << 4);

    // B pointers (w1 frag images); this wave's 2 ct columns
    const char* bhp = wsb + WS_W1H + ((size_t)(wv * 2) * 64 + lane) * 16;
    const char* blp = wsb + WS_W1L + ((size_t)(wv * 2) * 64 + lane) * 16;

    f32x4 acc[4][2];
    #pragma unroll
    for (int a = 0; a < 4; ++a)
        #pragma unroll
        for (int b = 0; b < 2; ++b)
            acc[a][b] = (f32x4){0.f, 0.f, 0.f, 0.f};

    short8 b0h[2], b0l[2], b1h[2], b1l[2], b2h[2], b2l[2];

    // ---- prologue: x(0..2) async; B(0),B(1) asm; convert(0) ----
    gload16(xg + gch * 4,       &sm.s.raw[0][wv * 1024]);
    gload16(xg + 32 + gch * 4,  &sm.s.raw[1][wv * 1024]);
    gload16(xg + 64 + gch * 4,  &sm.s.raw[2][wv * 1024]);
    b0h[0] = gload_s8(bhp);            b0h[1] = gload_s8(bhp + 1024);
    b0l[0] = gload_s8(blp);            b0l[1] = gload_s8(blp + 1024);
    b1h[0] = gload_s8(bhp + 16384);    b1h[1] = gload_s8(bhp + 16384 + 1024);
    b1l[0] = gload_s8(blp + 16384);    b1l[1] = gload_s8(blp + 16384 + 1024);
    // drain x(0),x(1); keep x(2)+B(0)+B(1) = 9 in flight
    asm volatile("s_waitcnt vmcnt(9)");
    __builtin_amdgcn_sched_barrier(0);
    __builtin_amdgcn_s_barrier();      // all waves' x(0),x(1) landed
    __builtin_amdgcn_sched_barrier(0);
    {   // convert(0) -> conv[0]
        const float4 f = *(const float4*)(sm.s.raw[0] + tid * 16);
        uint2 h, l;
        cvt4(f, &h, &l);
        *(uint2*)(sm.s.convh[0] + conv_off) = h;
        *(uint2*)(sm.s.convl[0] + conv_off) = l;
    }
    asm volatile("s_waitcnt lgkmcnt(0)");
    __builtin_amdgcn_sched_barrier(0);
    __builtin_amdgcn_s_barrier();
    __builtin_amdgcn_sched_barrier(0);

    // ---- main loop: kt = 0..23; per iter: issue x(kt+3), B(kt+2);
    //      vmcnt(9); convert(kt+1); MFMA(kt); lgkmcnt(0); barrier ----
#define BODY(KT, BHC, BLC, BHN, BLN)                                           \
    {                                                                          \
        const int kt = (KT);                                                   \
        const int kx = (kt + 3 > 24) ? 24 : kt + 3;                            \
        const int cg = (kx == 24 && gch > 3) ? 0 : gch;                        \
        gload16(xg + kx * 32 + cg * 4, &sm.s.raw[(kt + 3) & 3][wv * 1024]);    \
        const int kb2 = (kt + 2 > 24) ? 24 : kt + 2;                           \
        const char* bhq = bhp + (size_t)kb2 * 16384;                           \
        const char* blq = blp + (size_t)kb2 * 16384;                           \
        BHN[0] = gload_s8(bhq);  BHN[1] = gload_s8(bhq + 1024);                \
        BLN[0] = gload_s8(blq);  BLN[1] = gload_s8(blq + 1024);                \
        asm volatile("s_waitcnt vmcnt(9)");                                    \
        __builtin_amdgcn_sched_barrier(0);                                     \
        {                                                                      \
            const float4 f = *(const float4*)(sm.s.raw[(kt + 1) & 3] + tid * 16); \
            uint2 h, l;                                                        \
            cvt4(f, &h, &l);                                                   \
            *(uint2*)(sm.s.convh[(kt + 1) & 1] + conv_off) = h;                \
            *(uint2*)(sm.s.convl[(kt + 1) & 1] + conv_off) = l;                \
        }                                                                      \
        {                                                                      \
            const char* ch  = sm.s.convh[kt & 1];                              \
            const char* cl2 = sm.s.convl[kt & 1];                              \
            __builtin_amdgcn_s_setprio(1);                                     \
            _Pragma("unroll")                                                  \
            for (int rt = 0; rt < 4; ++rt) {                                   \
                const short8 ah = *(const short8*)(ch  + fbase + rt * 1024);   \
                const short8 al = *(const short8*)(cl2 + fbase + rt * 1024);   \
                _Pragma("unroll")                                              \
                for (int c = 0; c < 2; ++c) {                                  \
                    acc[rt][c] = __builtin_amdgcn_mfma_f32_16x16x32_bf16(ah, BHC[c], acc[rt][c], 0, 0, 0); \
                    acc[rt][c] = __builtin_amdgcn_mfma_f32_16x16x32_bf16(al, BHC[c], acc[rt][c], 0, 0, 0); \
                    acc[rt][c] = __builtin_amdgcn_mfma_f32_16x16x32_bf16(ah, BLC[c], acc[rt][c], 0, 0, 0); \
                }                                                              \
            }                                                                  \
            __builtin_amdgcn_s_setprio(0);                                     \
        }                                                                      \
        asm volatile("s_waitcnt lgkmcnt(0)");                                  \
        __builtin_amdgcn_sched_barrier(0);                                     \
        __builtin_amdgcn_s_barrier();                                          \
        __builtin_amdgcn_sched_barrier(0);                                     \
    }

    for (int kb = 0; kb < 24; kb += 3) {
        BODY(kb,     b0h, b0l, b2h, b2l);   // compute B0, fill B2 with kt+2
        BODY(kb + 1, b1h, b1l, b0h, b0l);
        BODY(kb + 2, b2h, b2l, b1h, b1l);
    }
#undef BODY

    // ---- tail kt = 24 (stage B0 holds B(24); conv[0] holds tile 24) ----
    {
        asm volatile("s_waitcnt vmcnt(0)");
        __builtin_amdgcn_sched_barrier(0);
        const char* ch  = sm.s.convh[0];
        const char* cl2 = sm.s.convl[0];
        __builtin_amdgcn_s_setprio(1);
        #pragma unroll
        for (int rt = 0; rt < 4; ++rt) {
            short8 ah = *(const short8*)(ch  + fbase + rt * 1024);
            short8 al = *(const short8*)(cl2 + fbase + rt * 1024);
            if (quad >= 2) {               // k >= 784: zero the A frags
                const short8 zz = {0, 0, 0, 0, 0, 0, 0, 0};
                ah = zz; al = zz;
            }
            #pragma unroll
            for (int c = 0; c < 2; ++c) {
                acc[rt][c] = __builtin_amdgcn_mfma_f32_16x16x32_bf16(ah, b0h[c], acc[rt][c], 0, 0, 0);
                acc[rt][c] = __builtin_amdgcn_mfma_f32_16x16x32_bf16(al, b0h[c], acc[rt][c], 0, 0, 0);
                acc[rt][c] = __builtin_amdgcn_mfma_f32_16x16x32_bf16(ah, b0l[c], acc[rt][c], 0, 0, 0);
            }
        }
        __builtin_amdgcn_s_setprio(0);
    }

    // ---- epilogue: single pass, hid = 64x256 (aliases staging) ----
    __syncthreads();                       // all staging reads done; async landed
    #pragma unroll
    for (int c = 0; c < 2; ++c) {
        const int g  = (wv * 2 + c) * 16 + m;
        const float bv = b1[g];
        #pragma unroll
        for (int rt = 0; rt < 4; ++rt)
            #pragma unroll
            for (int reg = 0; reg < 4; ++reg) {
                const int row = rt * 16 + quad * 4 + reg;
                sm.hid[row * 256 + (g ^ ((row & 7) << 2))] =
                    fmaxf(acc[rt][c][reg] + bv, 0.f);
            }
    }
    __syncthreads();

    const int rl    = tid >> 3;            // row 0..63
    const int slice = tid & 7;             // 8 col-slices of 32
    const int sw2   = (rl & 7) << 2;
    float lg[NCLS];
    #pragma unroll
    for (int k = 0; k < NCLS; ++k) lg[k] = 0.f;
    #pragma unroll
    for (int i = 0; i < 8; ++i) {
        const int col = slice * 32 + i * 4;
        const float4 h = *(const float4*)(sm.hid + rl * 256 + (col ^ sw2));
        #pragma unroll
        for (int k = 0; k < NCLS; ++k) {
            const float4 w = *(const float4*)(w2 + k * HID_F + col);
            lg[k] += h.x * w.x + h.y * w.y + h.z * w.z + h.w * w.w;
        }
    }
    #pragma unroll
    for (int k = 0; k < NCLS; ++k) {       // reduce 8 slices (lane bits 0..2)
        float v = lg[k];
        v += __shfl_xor(v, 1);
        v += __shfl_xor(v, 2);
        v += __shfl_xor(v, 4);
        lg[k] = v + b2[k];
    }
    float mx = -1e30f;
    #pragma unroll
    for (int k = 0; k < NCLS; ++k) mx = fmaxf(mx, lg[k]);
    float s = 0.f;
    #pragma unroll
    for (int k = 0; k < NCLS; ++k) { lg[k] = __expf(lg[k] - mx); s += lg[k]; }
    const float inv = 1.f / s;
    // select lg[slice] / lg[8+slice] without runtime register indexing
    const float va = (slice & 4)
        ? ((slice & 2) ? ((slice & 1) ? lg[7] : lg[6]) : ((slice & 1) ? lg[5] : lg[4]))
        : ((slice & 2) ? ((slice & 1) ? lg[3] : lg[2]) : ((slice & 1) ? lg[1] : lg[0]));
    const float vb = (slice & 1) ? lg[9] : lg[8];
    float* o = out + (size_t)(row0 + rl) * NCLS;
    o[slice] = va * inv;
    if (slice < 2) o[8 + slice] = vb * inv;
}

extern "C" void kernel_launch(void* const* d_in, const int* in_sizes, int n_in,
                              void* d_out, int out_size, void* d_ws, size_t ws_size,
                              hipStream_t stream)
{
    const float* x  = (const float*)d_in[0];
    const float* w1 = (const float*)d_in[1];
    const float* b1 = (const float*)d_in[2];
    const float* w2 = (const float*)d_in[3];
    const float* b2 = (const float*)d_in[4];
    float* out = (float*)d_out;

    hipLaunchKernelGGL(prep_w1_kernel, dim3(100), dim3(256), 0, stream,
                       w1, (char*)d_ws);
    hipLaunchKernelGGL(mlp_mfma_kernel, dim3(BATCH_N / BM), dim3(NTHREADS), 0, stream,
                       x, (const char*)d_ws, b1, w2, b2, out);
}

// Round 6
// 213.198 us; speedup vs baseline: 1.0565x; 1.0015x over previous
//
#include <hip/hip_runtime.h>
#include <math.h>

#define BATCH_N   32768
#define IN_F      784
#define HID_F     256
#define NCLS      10
#define BM        64          // batch rows per block
#define NTHREADS  512         // 8 waves: wave wv owns column tile ct = wv (32 cols)

typedef __attribute__((ext_vector_type(8)))  short short8;   // 8 bf16 = one 32x32x16 operand frag
typedef __attribute__((ext_vector_type(4)))  float f32x4;
typedef __attribute__((ext_vector_type(16))) float f32x16;   // 32x32 accumulator

// d_ws: w1 as split-bf16 frag images for 32x32x16 B-operand:
//   slot s = (kt*8 + ct)*64 + lane, 16 B: elems j=0..7 =
//   w1[ct*32 + (lane&31)][kt*16 + (lane>>5)*8 + j]   (784 = 49*16: no padding)
#define WS_W1H 0
#define WS_W1L 401408          // 49*8*64*16
// total ws use: 802816 bytes

union S8U { short8 s; uint4 u; };

__device__ __forceinline__ void cvt8(float4 a, float4 b, short8* hi, short8* lo) {
    const unsigned M = 0xFFFF0000u;
    const unsigned ux = __float_as_uint(a.x), uy = __float_as_uint(a.y),
                   uz = __float_as_uint(a.z), uw = __float_as_uint(a.w),
                   vx = __float_as_uint(b.x), vy = __float_as_uint(b.y),
                   vz = __float_as_uint(b.z), vw = __float_as_uint(b.w);
    S8U h, l;
    h.u.x = (ux >> 16) | (uy & M);
    h.u.y = (uz >> 16) | (uw & M);
    h.u.z = (vx >> 16) | (vy & M);
    h.u.w = (vz >> 16) | (vw & M);
    const float rx = a.x - __uint_as_float(ux & M);
    const float ry = a.y - __uint_as_float(uy & M);
    const float rz = a.z - __uint_as_float(uz & M);
    const float rw = a.w - __uint_as_float(uw & M);
    const float sx = b.x - __uint_as_float(vx & M);
    const float sy = b.y - __uint_as_float(vy & M);
    const float sz = b.z - __uint_as_float(vz & M);
    const float sw_ = b.w - __uint_as_float(vw & M);
    l.u.x = (__float_as_uint(rx) >> 16) | (__float_as_uint(ry) & M);
    l.u.y = (__float_as_uint(rz) >> 16) | (__float_as_uint(rw) & M);
    l.u.z = (__float_as_uint(sx) >> 16) | (__float_as_uint(sy) & M);
    l.u.w = (__float_as_uint(sz) >> 16) | (__float_as_uint(sw_) & M);
    *hi = h.s; *lo = l.s;
}

__device__ __forceinline__ void cvt8v(f32x4 a, f32x4 b, short8* hi, short8* lo) {
    float4 fa = make_float4(a[0], a[1], a[2], a[3]);
    float4 fb = make_float4(b[0], b[1], b[2], b[3]);
    cvt8(fa, fb, hi, lo);
}

// ---- pre-pass: w1 -> split-bf16 32-wide frag images (25088 slots) ----
__global__ __launch_bounds__(256)
void prep_w1_kernel(const float* __restrict__ w1, char* __restrict__ ws) {
    const int s    = blockIdx.x * 256 + threadIdx.x;   // 49*8*64 = 25088, grid 98
    const int lane = s & 63, ct = (s >> 6) & 7, kt = s >> 9;
    const int n    = ct * 32 + (lane & 31);
    const int k0   = kt * 16 + (lane >> 5) * 8;        // <= 783, always valid
    const float* p = w1 + (size_t)n * IN_F + k0;
    const float4 a = *(const float4*)p;
    const float4 b = *(const float4*)(p + 4);
    short8 hi, lo;
    cvt8(a, b, &hi, &lo);
    *(short8*)(ws + WS_W1H + (size_t)s * 16) = hi;
    *(short8*)(ws + WS_W1L + (size_t)s * 16) = lo;
}

// inline-asm 16B loads: compiler cannot sink/serialize; guarded by manual vmcnt.
// CONTRACT (r5 lesson): results may ONLY be consumed by instructions after the
// matching s_waitcnt; NO register copies of these destinations may exist.
__device__ __forceinline__ short8 gload_s8(const void* p) {
    short8 r;
    asm volatile("global_load_dwordx4 %0, %1, off" : "=v"(r) : "v"(p));
    return r;
}
__device__ __forceinline__ f32x4 gload_f4(const float* p) {
    f32x4 r;
    asm volatile("global_load_dwordx4 %0, %1, off" : "=v"(r) : "v"(p));
    return r;
}

#define MFMA32(A, B, C) __builtin_amdgcn_mfma_f32_32x32x16_bf16((A), (B), (C), 0, 0, 0)

// ---- main kernel: 32x32x16, fully-unrolled 49-step copy-free pipeline ----
__global__ __launch_bounds__(NTHREADS, 2)
void mlp_mfma_kernel(const float* __restrict__ x,
                     const char*  __restrict__ wsb,
                     const float* __restrict__ b1,
                     const float* __restrict__ w2,
                     const float* __restrict__ b2,
                     float* __restrict__ out)
{
    // stage[p]: xh at [ktl*2048 + row*32 + slot*16] (7 kt * 64 rows * 32 B),
    //           xl at +14336. slot = chunk ^ ((row>>2)&1).
    __shared__ union {
        char  stage[2][28672];    // 56 KB split-bf16 x tiles, double-buffered
        float hid[64 * 256];      // 64 KB epilogue (staging dead by then)
    } sm;

    const int tid   = threadIdx.x;
    const int lane  = tid & 63;
    const int wv    = tid >> 6;         // wave = column tile ct (0..7) -- dedup'd B
    const int l31   = lane & 31;
    const int khalf = lane >> 5;
    const int row0  = blockIdx.x * BM;

    // stager map: lane l -> row l, k-window ktl = wv (wave 7 loads dup, skips write)
    const int srow  = tid & 63;
    const int sktl  = (wv < 7) ? wv : 6;
    const float* xs = x + (size_t)(row0 + srow) * IN_F + sktl * 16;
    const int ssw   = (srow >> 2) & 1;
    const int swo0  = sktl * 2048 + srow * 32 + (0 ^ ssw) * 16;
    const int swo1  = sktl * 2048 + srow * 32 + (1 ^ ssw) * 16;

    // frag read: rt=0 rows 0..31 at aro, rt=1 rows 32..63 at aro+1024
    const int asw = (l31 >> 2) & 1;
    const int aro = l31 * 32 + ((khalf ^ asw) << 4);

    // B image pointers for this wave's single column tile (no duplication)
    const char* bhp = wsb + WS_W1H + ((size_t)wv * 64 + lane) * 16;
    const char* blp = wsb + WS_W1L + ((size_t)wv * 64 + lane) * 16;

    f32x16 acc0, acc1;
    #pragma unroll
    for (int r = 0; r < 16; ++r) { acc0[r] = 0.f; acc1[r] = 0.f; }

    // ---- prologue: x(round 0) + B(kt 0) into parity slot 0; convert round 0 ----
    f32x4 s0 = gload_f4(xs), s1 = gload_f4(xs + 4),
          s2 = gload_f4(xs + 8), s3 = gload_f4(xs + 12);
    short8 bh0, bl0, bh1, bl1;
    bh0 = gload_s8(bhp);
    bl0 = gload_s8(blp);
    asm volatile("s_waitcnt vmcnt(2)" ::: "memory");   // x landed; B(0) in flight
    __builtin_amdgcn_sched_barrier(0);
    if (wv < 7) {
        short8 h0, l0, h1, l1;
        cvt8v(s0, s1, &h0, &l0);
        cvt8v(s2, s3, &h1, &l1);
        char* st = sm.stage[0];
        *(short8*)(st + swo0)         = h0;
        *(short8*)(st + 14336 + swo0) = l0;
        *(short8*)(st + swo1)         = h1;
        *(short8*)(st + 14336 + swo1) = l1;
    }
    asm volatile("s_waitcnt lgkmcnt(0)" ::: "memory");
    __builtin_amdgcn_sched_barrier(0);
    __builtin_amdgcn_s_barrier();
    __builtin_amdgcn_sched_barrier(0);

    // ---- 7 rounds x 7 kt, FULLY unrolled (49 bodies, zero backedges).
    // vmcnt ledger (2 B loads/kt, 4 x loads at t=4, queue oldest-first):
    //  t0..t3: [B(kt)] +issue B(kt+1) -> 4; vmcnt(2) retires B(kt).
    //  t4: +B(kt+1), +x -> 8; vmcnt(6) retires B(kt).
    //  t5: [B5,x] +B6 -> 8; vmcnt(6) retires B5.
    //  t6: [x,B6] +B7 -> 8; vmcnt(2) retires x+B6. round end: [B7].
    //  g=6: no x issue -> vmcnt(2) everywhere; kt=48 issues nothing, vmcnt(0).
    #pragma unroll
    for (int g = 0; g < 7; ++g) {
        const char* bufr = sm.stage[g & 1];
        #pragma unroll
        for (int t = 0; t < 7; ++t) {
            const int kt = g * 7 + t;
            // issue B(kt+1) into parity slot (kt+1)&1 -- asm defs only, no copies
            if (kt < 48) {
                const char* pbh = bhp + (size_t)(kt + 1) * 8192;
                const char* pbl = blp + (size_t)(kt + 1) * 8192;
                if (kt & 1) { bh0 = gload_s8(pbh); bl0 = gload_s8(pbl); }
                else        { bh1 = gload_s8(pbh); bl1 = gload_s8(pbl); }
            }
            if (g < 6 && t == 4) {                    // stage next round's x
                const float* sp = xs + (g + 1) * 112;
                s0 = gload_f4(sp);      s1 = gload_f4(sp + 4);
                s2 = gload_f4(sp + 8);  s3 = gload_f4(sp + 12);
            }
            if (g < 6 && (t == 4 || t == 5)) {
                asm volatile("s_waitcnt vmcnt(6)" ::: "memory");
            } else if (kt == 48) {
                asm volatile("s_waitcnt vmcnt(0)" ::: "memory");
            } else {
                asm volatile("s_waitcnt vmcnt(2)" ::: "memory");
            }
            __builtin_amdgcn_sched_barrier(0);
            const short8 ah0 = *(const short8*)(bufr + t * 2048 + aro);
            const short8 al0 = *(const short8*)(bufr + 14336 + t * 2048 + aro);
            const short8 ah1 = *(const short8*)(bufr + t * 2048 + aro + 1024);
            const short8 al1 = *(const short8*)(bufr + 14336 + t * 2048 + aro + 1024);
            __builtin_amdgcn_s_setprio(1);
            if (kt & 1) {
                acc0 = MFMA32(ah0, bh1, acc0);
                acc0 = MFMA32(al0, bh1, acc0);
                acc0 = MFMA32(ah0, bl1, acc0);
                acc1 = MFMA32(ah1, bh1, acc1);
                acc1 = MFMA32(al1, bh1, acc1);
                acc1 = MFMA32(ah1, bl1, acc1);
            } else {
                acc0 = MFMA32(ah0, bh0, acc0);
                acc0 = MFMA32(al0, bh0, acc0);
                acc0 = MFMA32(ah0, bl0, acc0);
                acc1 = MFMA32(ah1, bh0, acc1);
                acc1 = MFMA32(al1, bh0, acc1);
                acc1 = MFMA32(ah1, bl0, acc1);
            }
            __builtin_amdgcn_s_setprio(0);
            __builtin_amdgcn_sched_barrier(0);
        }
        if (g < 6) {
            // convert next round's x (retired at t=6's vmcnt(2)) into other buffer
            if (wv < 7) {
                short8 h0, l0, h1, l1;
                cvt8v(s0, s1, &h0, &l0);
                cvt8v(s2, s3, &h1, &l1);
                char* st = sm.stage[(g + 1) & 1];
                *(short8*)(st + swo0)         = h0;
                *(short8*)(st + 14336 + swo0) = l0;
                *(short8*)(st + swo1)         = h1;
                *(short8*)(st + 14336 + swo1) = l1;
            }
            asm volatile("s_waitcnt lgkmcnt(0)" ::: "memory");
            __builtin_amdgcn_sched_barrier(0);
            __builtin_amdgcn_s_barrier();
            __builtin_amdgcn_sched_barrier(0);
        }
    }

    // ---- epilogue: bias + relu -> hid (32x32 C/D layout: col=lane&31,
    //      row = (reg&3) + 8*(reg>>2) + 4*(lane>>5)) ----
    __syncthreads();                       // last stage reads done; vmem drained
    {
        const int col = wv * 32 + l31;
        const float bv = b1[col];
        #pragma unroll
        for (int reg = 0; reg < 16; ++reg) {
            const int rowb = (reg & 3) + 8 * (reg >> 2) + 4 * khalf;   // 0..31
            sm.hid[rowb * 256 + (col ^ ((rowb & 7) << 2))] =
                fmaxf(acc0[reg] + bv, 0.f);
            const int rowc = 32 + rowb;
            sm.hid[rowc * 256 + (col ^ ((rowc & 7) << 2))] =
                fmaxf(acc1[reg] + bv, 0.f);
        }
    }
    __syncthreads();

    // ---- phase 2: logits + softmax (verified epilogue, unchanged) ----
    const int rl    = tid >> 3;            // row 0..63
    const int slice = tid & 7;             // 8 col-slices of 32
    const int sw2   = (rl & 7) << 2;
    float lg[NCLS];
    #pragma unroll
    for (int k = 0; k < NCLS; ++k) lg[k] = 0.f;
    #pragma unroll
    for (int i = 0; i < 8; ++i) {
        const int col = slice * 32 + i * 4;
        const float4 h = *(const float4*)(sm.hid + rl * 256 + (col ^ sw2));
        #pragma unroll
        for (int k = 0; k < NCLS; ++k) {
            const float4 w = *(const float4*)(w2 + k * HID_F + col);
            lg[k] += h.x * w.x + h.y * w.y + h.z * w.z + h.w * w.w;
        }
    }
    #pragma unroll
    for (int k = 0; k < NCLS; ++k) {       // reduce 8 slices (lane bits 0..2)
        float v = lg[k];
        v += __shfl_xor(v, 1);
        v += __shfl_xor(v, 2);
        v += __shfl_xor(v, 4);
        lg[k] = v + b2[k];
    }
    float mx = -1e30f;
    #pragma unroll
    for (int k = 0; k < NCLS; ++k) mx = fmaxf(mx, lg[k]);
    float s = 0.f;
    #pragma unroll
    for (int k = 0; k < NCLS; ++k) { lg[k] = __expf(lg[k] - mx); s += lg[k]; }
    const float inv = 1.f / s;
    // select lg[slice] / lg[8+slice] without runtime register indexing
    const float va = (slice & 4)
        ? ((slice & 2) ? ((slice & 1) ? lg[7] : lg[6]) : ((slice & 1) ? lg[5] : lg[4]))
        : ((slice & 2) ? ((slice & 1) ? lg[3] : lg[2]) : ((slice & 1) ? lg[1] : lg[0]));
    const float vb = (slice & 1) ? lg[9] : lg[8];
    float* o = out + (size_t)(row0 + rl) * NCLS;
    o[slice] = va * inv;
    if (slice < 2) o[8 + slice] = vb * inv;
}

extern "C" void kernel_launch(void* const* d_in, const int* in_sizes, int n_in,
                              void* d_out, int out_size, void* d_ws, size_t ws_size,
                              hipStream_t stream)
{
    const float* x  = (const float*)d_in[0];
    const float* w1 = (const float*)d_in[1];
    const float* b1 = (const float*)d_in[2];
    const float* w2 = (const float*)d_in[3];
    const float* b2 = (const float*)d_in[4];
    float* out = (float*)d_out;

    // pre-pass: w1 -> split-bf16 32-wide frag images (98 blocks x 256)
    hipLaunchKernelGGL(prep_w1_kernel, dim3(98), dim3(256), 0, stream,
                       w1, (char*)d_ws);
    // main fused MLP
    hipLaunchKernelGGL(mlp_mfma_kernel, dim3(BATCH_N / BM), dim3(NTHREADS), 0, stream,
                       x, (const char*)d_ws, b1, w2, b2, out);
}

// Round 7
// 187.653 us; speedup vs baseline: 1.2003x; 1.1361x over previous
//
#include <hip/hip_runtime.h>
#include <math.h>

#define BATCH_N   32768
#define IN_F      784
#define HID_F     256
#define NCLS      10
#define BM        128         // batch rows per block (2x r6: B reused across 4 row-tiles)
#define NTHREADS  512         // 8 waves: wave wv owns column tile ct = wv (32 cols), all 4 row-tiles

typedef __attribute__((ext_vector_type(8)))  short short8;   // 8 bf16 = one 32x32x16 operand frag
typedef __attribute__((ext_vector_type(4)))  float f32x4;
typedef __attribute__((ext_vector_type(16))) float f32x16;   // 32x32 accumulator

// d_ws: w1 as split-bf16 frag images for 32x32x16 B-operand (verified r6):
//   slot s = (kt*8 + ct)*64 + lane, 16 B: elems j=0..7 =
//   w1[ct*32 + (lane&31)][kt*16 + (lane>>5)*8 + j]   (784 = 49*16: no padding)
#define WS_W1H 0
#define WS_W1L 401408          // 49*8*64*16

union S8U { short8 s; uint4 u; };

__device__ __forceinline__ void cvt8(float4 a, float4 b, short8* hi, short8* lo) {
    const unsigned M = 0xFFFF0000u;
    const unsigned ux = __float_as_uint(a.x), uy = __float_as_uint(a.y),
                   uz = __float_as_uint(a.z), uw = __float_as_uint(a.w),
                   vx = __float_as_uint(b.x), vy = __float_as_uint(b.y),
                   vz = __float_as_uint(b.z), vw = __float_as_uint(b.w);
    S8U h, l;
    h.u.x = (ux >> 16) | (uy & M);
    h.u.y = (uz >> 16) | (uw & M);
    h.u.z = (vx >> 16) | (vy & M);
    h.u.w = (vz >> 16) | (vw & M);
    const float rx = a.x - __uint_as_float(ux & M);
    const float ry = a.y - __uint_as_float(uy & M);
    const float rz = a.z - __uint_as_float(uz & M);
    const float rw = a.w - __uint_as_float(uw & M);
    const float sx = b.x - __uint_as_float(vx & M);
    const float sy = b.y - __uint_as_float(vy & M);
    const float sz = b.z - __uint_as_float(vz & M);
    const float sw_ = b.w - __uint_as_float(vw & M);
    l.u.x = (__float_as_uint(rx) >> 16) | (__float_as_uint(ry) & M);
    l.u.y = (__float_as_uint(rz) >> 16) | (__float_as_uint(rw) & M);
    l.u.z = (__float_as_uint(sx) >> 16) | (__float_as_uint(sy) & M);
    l.u.w = (__float_as_uint(sz) >> 16) | (__float_as_uint(sw_) & M);
    *hi = h.s; *lo = l.s;
}

__device__ __forceinline__ void cvt8v(f32x4 a, f32x4 b, short8* hi, short8* lo) {
    float4 fa = make_float4(a[0], a[1], a[2], a[3]);
    float4 fb = make_float4(b[0], b[1], b[2], b[3]);
    cvt8(fa, fb, hi, lo);
}

// ---- pre-pass: w1 -> split-bf16 32-wide frag images (verified r6) ----
__global__ __launch_bounds__(256)
void prep_w1_kernel(const float* __restrict__ w1, char* __restrict__ ws) {
    const int s    = blockIdx.x * 256 + threadIdx.x;   // 49*8*64 = 25088, grid 98
    const int lane = s & 63, ct = (s >> 6) & 7, kt = s >> 9;
    const int n    = ct * 32 + (lane & 31);
    const int k0   = kt * 16 + (lane >> 5) * 8;
    const float* p = w1 + (size_t)n * IN_F + k0;
    const float4 a = *(const float4*)p;
    const float4 b = *(const float4*)(p + 4);
    short8 hi, lo;
    cvt8(a, b, &hi, &lo);
    *(short8*)(ws + WS_W1H + (size_t)s * 16) = hi;
    *(short8*)(ws + WS_W1L + (size_t)s * 16) = lo;
}

// inline-asm 16B loads; results consumed only after the matching manual vmcnt,
// and NEVER copied between registers while in flight (r5 contract).
__device__ __forceinline__ short8 gload_s8(const void* p) {
    short8 r;
    asm volatile("global_load_dwordx4 %0, %1, off" : "=v"(r) : "v"(p));
    return r;
}
__device__ __forceinline__ f32x4 gload_f4(const float* p) {
    f32x4 r;
    asm volatile("global_load_dwordx4 %0, %1, off" : "=v"(r) : "v"(p));
    return r;
}

#define MFMA32(A, B, C) __builtin_amdgcn_mfma_f32_32x32x16_bf16((A), (B), (C), 0, 0, 0)

// one K-tile (K=16): 8 LDS frag reads (4 row-tiles x hi/lo) + 12 MFMAs
#define MFMA_KT(BUF, KTL, BH, BL)                                              \
    {                                                                          \
        __builtin_amdgcn_s_setprio(1);                                         \
        _Pragma("unroll")                                                      \
        for (int rt = 0; rt < 4; ++rt) {                                       \
            const short8 ah = *(const short8*)((BUF) + (KTL) * 4096 + rt * 1024 + aro); \
            const short8 al = *(const short8*)((BUF) + 16384 + (KTL) * 4096 + rt * 1024 + aro); \
            acc[rt] = MFMA32(ah, BH, acc[rt]);                                 \
            acc[rt] = MFMA32(al, BH, acc[rt]);                                 \
            acc[rt] = MFMA32(ah, BL, acc[rt]);                                 \
        }                                                                      \
        __builtin_amdgcn_s_setprio(0);                                         \
    }

// x issue for next round (4 chunks of 8 floats: j = sq and sq+4)
#define XISSUE4(G) do {                                                        \
        s0 = gload_f4(xs + ((G) + 1) * 64 + sq * 8);                           \
        s1 = gload_f4(xs + ((G) + 1) * 64 + sq * 8 + 4);                       \
        s2 = gload_f4(xs + ((G) + 1) * 64 + 32 + sq * 8);                      \
        s3 = gload_f4(xs + ((G) + 1) * 64 + 32 + sq * 8 + 4);                  \
    } while (0)
// tail x issue (16 k only; uniform 2 loads/thread, sq>=2 load duplicates)
#define XISSUET() do {                                                         \
        s0 = gload_f4(xs + 768 + (sq & 1) * 8);                                \
        s1 = gload_f4(xs + 768 + (sq & 1) * 8 + 4);                            \
    } while (0)
// convert staged x (4 chunks) into write buffer
#define CVT4W(BW) do {                                                         \
        short8 h0, l0, h1, l1;                                                 \
        cvt8v(s0, s1, &h0, &l0);                                               \
        cvt8v(s2, s3, &h1, &l1);                                               \
        *(short8*)((BW) + wo0)         = h0;                                   \
        *(short8*)((BW) + 16384 + wo0) = l0;                                   \
        *(short8*)((BW) + wo1)         = h1;                                   \
        *(short8*)((BW) + 16384 + wo1) = l1;                                   \
    } while (0)
#define CVTTW(BW) do {                                                         \
        short8 h0, l0;                                                         \
        cvt8v(s0, s1, &h0, &l0);                                               \
        if (sq < 2) {                                                          \
            *(short8*)((BW) + wot)         = h0;                               \
            *(short8*)((BW) + 16384 + wot) = l0;                               \
        }                                                                      \
    } while (0)

// Round of 4 kt. Entry invariant: outstanding VMEM = [B(4G): 2 loads].
// Ledger (oldest-first):
//  t0: +B1           -> [B0,B1]       ; vmcnt(2) retires B0
//  t1: +B2, +x(XN)   -> [B1,B2,x]     ; W1 (=2+XN) retires B1
//  t2: +B3           -> [B2,x,B3]     ; W1 retires B2
//  t3: +B4           -> [x,B3,B4]     ; vmcnt(2) retires x+B3 (B4 = next round)
//  cvt x -> other buffer; lgkmcnt(0); barrier.   Exit: [B4: 2]  (invariant)
// Bank parity: kt&1 = t&1 (4G even) -> E/O static names, no copies, full unroll.
#define ROUND(G, W1, XI, CVTW)                                                 \
    {                                                                          \
        const char* bufr = sm.stage[(G) & 1];                                  \
        char* bufw = sm.stage[((G) + 1) & 1];                                  \
        bhO = gload_s8(bhp + (size_t)(4 * (G) + 1) * 8192);                    \
        blO = gload_s8(blp + (size_t)(4 * (G) + 1) * 8192);                    \
        asm volatile("s_waitcnt vmcnt(2)" ::: "memory");                       \
        __builtin_amdgcn_sched_barrier(0);                                     \
        MFMA_KT(bufr, 0, bhE, blE);                                            \
        bhE = gload_s8(bhp + (size_t)(4 * (G) + 2) * 8192);                    \
        blE = gload_s8(blp + (size_t)(4 * (G) + 2) * 8192);                    \
        XI;                                                                    \
        asm volatile(W1 ::: "memory");                                         \
        __builtin_amdgcn_sched_barrier(0);                                     \
        MFMA_KT(bufr, 1, bhO, blO);                                            \
        bhO = gload_s8(bhp + (size_t)(4 * (G) + 3) * 8192);                    \
        blO = gload_s8(blp + (size_t)(4 * (G) + 3) * 8192);                    \
        asm volatile(W1 ::: "memory");                                         \
        __builtin_amdgcn_sched_barrier(0);                                     \
        MFMA_KT(bufr, 2, bhE, blE);                                            \
        bhE = gload_s8(bhp + (size_t)(4 * (G) + 4) * 8192);                    \
        blE = gload_s8(blp + (size_t)(4 * (G) + 4) * 8192);                    \
        asm volatile("s_waitcnt vmcnt(2)" ::: "memory");                       \
        __builtin_amdgcn_sched_barrier(0);                                     \
        MFMA_KT(bufr, 3, bhO, blO);                                            \
        CVTW(bufw);                                                            \
        asm volatile("s_waitcnt lgkmcnt(0)" ::: "memory");                     \
        __builtin_amdgcn_sched_barrier(0);                                     \
        __builtin_amdgcn_s_barrier();                                          \
        __builtin_amdgcn_sched_barrier(0);                                     \
    }

__global__ __launch_bounds__(NTHREADS, 2)
void mlp_mfma_kernel(const float* __restrict__ x,
                     const char*  __restrict__ wsb,
                     const float* __restrict__ b1,
                     const float* __restrict__ w2,
                     const float* __restrict__ b2,
                     float* __restrict__ out)
{
    // stage[p]: hi at [ktl*4096 + row*32 + slot*16] (4 kt x 128 rows x 32 B),
    // lo at +16384; slot = khalf ^ ((row>>2)&1). hid aliases both buffers.
    __shared__ union {
        char  stage[2][32768];    // 64 KB x tiles (K=64 window), double-buffered
        float hid[64 * 256];      // 64 KB epilogue half-tile
    } sm;

    const int tid   = threadIdx.x;
    const int lane  = tid & 63;
    const int wv    = tid >> 6;         // column tile ct = wv (dedup'd B)
    const int l31   = lane & 31;
    const int khalf = lane >> 5;
    const int row0  = blockIdx.x * BM;

    // stager map: thread -> row sr = tid>>2 (0..127), quarter sq = tid&3;
    // handles 8-float chunks j = sq and sq+4 of the 64-k round window.
    const int sr  = tid >> 2;
    const int sq  = tid & 3;
    const float* xs = x + (size_t)(row0 + sr) * IN_F;
    const int ssw = (sr >> 2) & 1;
    const int wo0 = (sq >> 1) * 4096 + sr * 32 + (((sq & 1) ^ ssw) << 4);
    const int wo1 = wo0 + 8192;                        // ktl + 2
    const int wot = sr * 32 + ((sq ^ ssw) << 4);       // tail: ktl=0, half=sq(<2)

    // frag read: row = rt*32 + l31 -> + rt*1024; k-half khalf with same swizzle
    const int asw = (l31 >> 2) & 1;
    const int aro = l31 * 32 + ((khalf ^ asw) << 4);

    // B image pointers for this wave's column tile
    const char* bhp = wsb + WS_W1H + ((size_t)wv * 64 + lane) * 16;
    const char* blp = wsb + WS_W1L + ((size_t)wv * 64 + lane) * 16;

    f32x16 acc[4];
    #pragma unroll
    for (int rt = 0; rt < 4; ++rt)
        #pragma unroll
        for (int r = 0; r < 16; ++r) acc[rt][r] = 0.f;

    short8 bhE, blE, bhO, blO;
    f32x4 s0, s1, s2, s3;

    // ---- prologue: x(round 0) 4 loads, B(kt0) 2 loads; cvt round 0 -> buf0 ----
    s0 = gload_f4(xs + sq * 8);
    s1 = gload_f4(xs + sq * 8 + 4);
    s2 = gload_f4(xs + 32 + sq * 8);
    s3 = gload_f4(xs + 32 + sq * 8 + 4);
    bhE = gload_s8(bhp);
    blE = gload_s8(blp);
    asm volatile("s_waitcnt vmcnt(2)" ::: "memory");   // x landed; B(0) in flight
    __builtin_amdgcn_sched_barrier(0);
    CVT4W(sm.stage[0]);
    asm volatile("s_waitcnt lgkmcnt(0)" ::: "memory");
    __builtin_amdgcn_sched_barrier(0);
    __builtin_amdgcn_s_barrier();
    __builtin_amdgcn_sched_barrier(0);

    // ---- 12 rounds x 4 kt (kt 0..47), fully unrolled, then tail kt=48 ----
    ROUND(0,  "s_waitcnt vmcnt(6)", XISSUE4(0),  CVT4W)
    ROUND(1,  "s_waitcnt vmcnt(6)", XISSUE4(1),  CVT4W)
    ROUND(2,  "s_waitcnt vmcnt(6)", XISSUE4(2),  CVT4W)
    ROUND(3,  "s_waitcnt vmcnt(6)", XISSUE4(3),  CVT4W)
    ROUND(4,  "s_waitcnt vmcnt(6)", XISSUE4(4),  CVT4W)
    ROUND(5,  "s_waitcnt vmcnt(6)", XISSUE4(5),  CVT4W)
    ROUND(6,  "s_waitcnt vmcnt(6)", XISSUE4(6),  CVT4W)
    ROUND(7,  "s_waitcnt vmcnt(6)", XISSUE4(7),  CVT4W)
    ROUND(8,  "s_waitcnt vmcnt(6)", XISSUE4(8),  CVT4W)
    ROUND(9,  "s_waitcnt vmcnt(6)", XISSUE4(9),  CVT4W)
    ROUND(10, "s_waitcnt vmcnt(6)", XISSUE4(10), CVT4W)
    ROUND(11, "s_waitcnt vmcnt(4)", XISSUET(),   CVTTW)   // tail x: 2 loads
    {   // tail kt = 48 (buffer 0, ktl 0; B(48) issued at round 11 t3, bank E)
        asm volatile("s_waitcnt vmcnt(0)" ::: "memory");
        __builtin_amdgcn_sched_barrier(0);
        MFMA_KT(sm.stage[0], 0, bhE, blE);
    }

    // ---- epilogue: two halves of 64 rows; verified layout + rotation fix ----
    const int rl    = tid >> 3;        // row 0..63 (within half)
    const int slice = tid & 7;         // 8 col-slices of 32
    const int sw2   = (rl & 7) << 2;

    #pragma unroll
    for (int half = 0; half < 2; ++half) {
        __syncthreads();               // half0: staging reads done; half1: phase-2 reads done
        // phase 1: bias + relu -> hid (rows half*64 .. half*64+63)
        {
            const int col = wv * 32 + l31;
            const float bv = b1[col];
            #pragma unroll
            for (int rr = 0; rr < 2; ++rr) {
                const int rt = half * 2 + rr;
                #pragma unroll
                for (int reg = 0; reg < 16; ++reg) {
                    // C/D: col = lane&31, row = (reg&3) + 8*(reg>>2) + 4*(lane>>5)
                    const int row = rr * 32 + (reg & 3) + 8 * (reg >> 2) + 4 * khalf;
                    sm.hid[row * 256 + (col ^ ((row & 7) << 2))] =
                        fmaxf(acc[rt][reg] + bv, 0.f);
                }
            }
        }
        __syncthreads();
        // phase 2: logits + softmax for this half's 64 rows
        float lg[NCLS];
        #pragma unroll
        for (int k = 0; k < NCLS; ++k) lg[k] = 0.f;
        #pragma unroll
        for (int i = 0; i < 8; ++i) {
            const int ii  = ((i + slice) & 7) * 4;     // rotation: spreads bank quads
            const int col = slice * 32 + ii;
            const float4 h = *(const float4*)(sm.hid + rl * 256 + (slice * 32 + (ii ^ sw2)));
            #pragma unroll
            for (int k = 0; k < NCLS; ++k) {
                const float4 w = *(const float4*)(w2 + k * HID_F + col);
                lg[k] += h.x * w.x + h.y * w.y + h.z * w.z + h.w * w.w;
            }
        }
        #pragma unroll
        for (int k = 0; k < NCLS; ++k) {   // reduce 8 slices (lane bits 0..2)
            float v = lg[k];
            v += __shfl_xor(v, 1);
            v += __shfl_xor(v, 2);
            v += __shfl_xor(v, 4);
            lg[k] = v + b2[k];
        }
        float mx = -1e30f;
        #pragma unroll
        for (int k = 0; k < NCLS; ++k) mx = fmaxf(mx, lg[k]);
        float s = 0.f;
        #pragma unroll
        for (int k = 0; k < NCLS; ++k) { lg[k] = __expf(lg[k] - mx); s += lg[k]; }
        const float inv = 1.f / s;
        const float va = (slice & 4)
            ? ((slice & 2) ? ((slice & 1) ? lg[7] : lg[6]) : ((slice & 1) ? lg[5] : lg[4]))
            : ((slice & 2) ? ((slice & 1) ? lg[3] : lg[2]) : ((slice & 1) ? lg[1] : lg[0]));
        const float vb = (slice & 1) ? lg[9] : lg[8];
        float* o = out + (size_t)(row0 + half * 64 + rl) * NCLS;
        o[slice] = va * inv;
        if (slice < 2) o[8 + slice] = vb * inv;
    }
}

extern "C" void kernel_launch(void* const* d_in, const int* in_sizes, int n_in,
                              void* d_out, int out_size, void* d_ws, size_t ws_size,
                              hipStream_t stream)
{
    const float* x  = (const float*)d_in[0];
    const float* w1 = (const float*)d_in[1];
    const float* b1 = (const float*)d_in[2];
    const float* w2 = (const float*)d_in[3];
    const float* b2 = (const float*)d_in[4];
    float* out = (float*)d_out;

    // pre-pass: w1 -> split-bf16 32-wide frag images (98 blocks x 256)
    hipLaunchKernelGGL(prep_w1_kernel, dim3(98), dim3(256), 0, stream,
                       w1, (char*)d_ws);
    // main fused MLP: 256 blocks x 512 threads, BM=128
    hipLaunchKernelGGL(mlp_mfma_kernel, dim3(BATCH_N / BM), dim3(NTHREADS), 0, stream,
                       x, (const char*)d_ws, b1, w2, b2, out);
}